// Round 9
// baseline (471.772 us; speedup 1.0000x reference)
//
#include <hip/hip_runtime.h>

typedef unsigned short u16;
typedef unsigned int u32;

typedef __bf16 bf16x8 __attribute__((ext_vector_type(8)));
typedef float f32x4 __attribute__((ext_vector_type(4)));

union V16 { uint4 u; bf16x8 v; u16 s[8]; __bf16 h[8]; };
union F4  { float4 v; float f[4]; };

__device__ __forceinline__ float bf2f(u16 a) {
  union { u32 u; float f; } c; c.u = ((u32)a) << 16; return c.f;
}

#define Z_OFF   131072
#define ZM_OFF  147456
#define ZLV_OFF 163840

// ws layout in uint4 units.
#define B1_OFF 0        // gen1_w frags: t<20, s<2
#define B2_OFF 2560     // gen2_w frags: t<20, s<10
#define E1_OFF 15360    // enc1_w frags: t<20, s<16
#define E2_OFF 35840    // enc2_w frags: t<20, s<10
#define ZMP_OFF 48640   // zm_w frags: t<4, s<10
#define ZVP_OFF 51200   // zv_w frags: t<4, s<10
#define FRAG_TOTAL 53760
#define WB4  53760      // W bf16 [512][64]   : 4096
#define XB4  57856      // x bf16 [256][512]  : 16384
#define H1_4 74240      // h1 bf16 [256][320] : 10240
#define H2_4 84480      // h2 bf16 [256][320] : 10240
#define PACK_ITEMS 74240
#define BAR_U4 94720    // barrier u32 lives at byte 94720*16
#define NWG 512
#define NTHR 320

__device__ __forceinline__ void pack_one(const float* __restrict__ src,
                                         int t, int s, int lane,
                                         int Nsrc, int Ksrc, int rowlen,
                                         uint4* __restrict__ dst) {
  const int n = t * 16 + (lane & 15);
  const int k0 = s * 32 + ((lane >> 4) << 3);
  V16 v;
#pragma unroll
  for (int j = 0; j < 8; ++j) {
    const int k = k0 + j;
    v.h[j] = (n < Nsrc && k < Ksrc) ? (__bf16)src[n * rowlen + k] : (__bf16)0.f;
  }
  *dst = v.u;
}

__device__ __forceinline__ void cvt8(const float* __restrict__ src, uint4* __restrict__ dst) {
  F4 a, b; a.v = *(const float4*)src; b.v = *(const float4*)(src + 4);
  V16 v;
#pragma unroll
  for (int j = 0; j < 4; ++j) { v.h[j] = (__bf16)a.f[j]; v.h[4 + j] = (__bf16)b.f[j]; }
  *dst = v.u;
}

// Software grid barrier: monotonic counter, agent-scope. All NWG WGs are
// co-resident by construction (LDS 21KB, VGPR<=128, 5 waves/WG -> >=768 slots).
__device__ __forceinline__ void gbar(u32* bar, u32 target, int tid) {
  __syncthreads();
  if (tid == 0) {
    __threadfence();   // device-scope release of all prior writes
    __hip_atomic_fetch_add(bar, 1u, __ATOMIC_RELEASE, __HIP_MEMORY_SCOPE_AGENT);
    u32 v;
    do {
      __builtin_amdgcn_s_sleep(4);
      v = __hip_atomic_load(bar, __ATOMIC_ACQUIRE, __HIP_MEMORY_SCOPE_AGENT);
    } while (v < target);
  }
  __syncthreads();
}

__global__ __launch_bounds__(NTHR, 4) void fused_kernel(
    const float* __restrict__ x, const float* __restrict__ eps,
    const float* __restrict__ e1w, const float* __restrict__ e1b,
    const float* __restrict__ e2w, const float* __restrict__ e2b,
    const float* __restrict__ zmw, const float* __restrict__ zmb,
    const float* __restrict__ zvw, const float* __restrict__ zvb,
    const float* __restrict__ g1w, const float* __restrict__ g2w,
    const float* __restrict__ g2b, const float* __restrict__ hw,
    const float* __restrict__ hb, const float* __restrict__ W,
    uint4* __restrict__ ws4, float* __restrict__ out) {
  __shared__ u16 g1s[32 * 328];     // 20,992 B; xred aliases after barrier
  float* xredf = (float*)g1s;

  u32* bar = (u32*)(ws4 + BAR_U4);
  const int wgid = blockIdx.x;
  const int tid = threadIdx.x;
  const int lane = tid & 63;
  const int q = lane >> 4;
  const int c = lane & 15;
  const int gw = wgid * 5 + (tid >> 6);   // global wave id (0..2559)

  // ---------------- P0: pack all fragment tables + Wb + xb ----------------
  {
    const int idx = wgid * NTHR + tid;
    if (idx < PACK_ITEMS) {
      const int l = idx & 63;
      if (idx < B2_OFF) {
        const int f = idx >> 6;
        pack_one(g1w, f >> 1, f & 1, l, 300, 64, 64, ws4 + idx);
      } else if (idx < E1_OFF) {
        const int f = (idx - B2_OFF) >> 6;
        pack_one(g2w, f / 10, f % 10, l, 300, 300, 300, ws4 + idx);
      } else if (idx < E2_OFF) {
        const int f = (idx - E1_OFF) >> 6;
        pack_one(e1w, f >> 4, f & 15, l, 300, 512, 512, ws4 + idx);
      } else if (idx < ZMP_OFF) {
        const int f = (idx - E2_OFF) >> 6;
        pack_one(e2w, f / 10, f % 10, l, 300, 300, 300, ws4 + idx);
      } else if (idx < ZVP_OFF) {
        const int f = (idx - ZMP_OFF) >> 6;
        pack_one(zmw, f / 10, f % 10, l, 64, 300, 300, ws4 + idx);
      } else if (idx < FRAG_TOTAL) {
        const int f = (idx - ZVP_OFF) >> 6;
        pack_one(zvw, f / 10, f % 10, l, 64, 300, 300, ws4 + idx);
      } else if (idx < XB4) {
        const int i = idx - WB4;
        cvt8(W + i * 8, ws4 + WB4 + i);
      } else {
        const int i = idx - XB4;
        cvt8(x + i * 8, ws4 + XB4 + i);
      }
    }
  }
  gbar(bar, 1 * NWG, tid);

  // ---------------- P1: enc1 (320 wave-jobs: rt<16 x nt<20) ----------------
  if (gw < 320) {
    const uint4* xb = ws4 + XB4;
    const uint4* e1p = ws4 + E1_OFF;
    u16* h1 = (u16*)(ws4 + H1_4);
    const int rt = gw / 20, nt = gw % 20;
    f32x4 acc = {0.f, 0.f, 0.f, 0.f};
    const int arow = rt * 16 + c;
#pragma unroll
    for (int s = 0; s < 16; ++s) {
      V16 a, b;
      a.u = xb[arow * 64 + s * 4 + q];
      b.u = e1p[(nt * 16 + s) * 64 + lane];
      acc = __builtin_amdgcn_mfma_f32_16x16x32_bf16(a.v, b.v, acc, 0, 0, 0);
    }
    const int col = nt * 16 + c;
    const float bias = (col < 300) ? e1b[col] : 0.f;
#pragma unroll
    for (int i = 0; i < 4; ++i) {
      const int row = rt * 16 + 4 * q + i;
      V16 t; t.h[0] = (col < 300) ? (__bf16)fmaxf(acc[i] + bias, 0.f) : (__bf16)0.f;
      h1[row * 320 + col] = t.s[0];
    }
  }
  gbar(bar, 2 * NWG, tid);

  // ---------------- P2: enc2 (320 wave-jobs) ----------------
  if (gw < 320) {
    const uint4* h1 = ws4 + H1_4;
    const uint4* e2p = ws4 + E2_OFF;
    u16* h2 = (u16*)(ws4 + H2_4);
    const int rt = gw / 20, nt = gw % 20;
    f32x4 acc = {0.f, 0.f, 0.f, 0.f};
    const int arow = rt * 16 + c;
#pragma unroll
    for (int s = 0; s < 10; ++s) {
      V16 a, b;
      a.u = h1[arow * 40 + s * 4 + q];
      b.u = e2p[(nt * 10 + s) * 64 + lane];
      acc = __builtin_amdgcn_mfma_f32_16x16x32_bf16(a.v, b.v, acc, 0, 0, 0);
    }
    const int col = nt * 16 + c;
    const float bias = (col < 300) ? e2b[col] : 0.f;
#pragma unroll
    for (int i = 0; i < 4; ++i) {
      const int row = rt * 16 + 4 * q + i;
      V16 t; t.h[0] = (col < 300) ? (__bf16)fmaxf(acc[i] + bias, 0.f) : (__bf16)0.f;
      h2[row * 320 + col] = t.s[0];
    }
  }
  gbar(bar, 3 * NWG, tid);

  // ---------------- P3: heads + reparameterize (64 wave-jobs) ----------------
  if (gw < 64) {
    const uint4* h2 = ws4 + H2_4;
    const uint4* zmp = ws4 + ZMP_OFF;
    const uint4* zvp = ws4 + ZVP_OFF;
    const int rt = gw >> 2, t = gw & 3;
    f32x4 am = {0.f, 0.f, 0.f, 0.f}, av = {0.f, 0.f, 0.f, 0.f};
    const int arow = rt * 16 + c;
#pragma unroll
    for (int s = 0; s < 10; ++s) {
      V16 a, bm, bv;
      a.u = h2[arow * 40 + s * 4 + q];
      bm.u = zmp[(t * 10 + s) * 64 + lane];
      bv.u = zvp[(t * 10 + s) * 64 + lane];
      am = __builtin_amdgcn_mfma_f32_16x16x32_bf16(a.v, bm.v, am, 0, 0, 0);
      av = __builtin_amdgcn_mfma_f32_16x16x32_bf16(a.v, bv.v, av, 0, 0, 0);
    }
    const int col = t * 16 + c;
    const float bm = zmb[col], bv = zvb[col];
#pragma unroll
    for (int i = 0; i < 4; ++i) {
      const int gi = (rt * 16 + 4 * q + i) * 64 + col;
      const float zm = am[i] + bm;
      const float zlv = av[i] + bv;
      out[ZM_OFF + gi] = zm;
      out[ZLV_OFF + gi] = zlv;
      out[Z_OFF + gi] = zm + eps[gi] * expf(0.5f * zlv);
    }
  }
  gbar(bar, 4 * NWG, tid);

  // ---------------- P4: decoder, 4096 virtual tiles, 8 per WG ----------------
  const float* z = out + Z_OFF;
  const uint4* Wb = ws4 + WB4;
  const uint4* b1p = ws4 + B1_OFF;
  const uint4* b2p = ws4 + B2_OFF;
  const int u = tid >> 6;

  for (int vt = wgid; vt < 4096; vt += NWG) {
    const int r0 = vt << 5;
    const int bi = vt >> 4;
    const int d0 = r0 & 511;
    const float* zrow = z + bi * 64;

    // ---- stage 2 ----
    bf16x8 bz[4][2];
#pragma unroll
    for (int kf = 0; kf < 2; ++kf) {
      F4 z0, z1;
      z0.v = *(const float4*)(zrow + kf * 32 + q * 8);
      z1.v = *(const float4*)(zrow + kf * 32 + q * 8 + 4);
#pragma unroll
      for (int tt = 0; tt < 4; ++tt) {
        V16 r; r.u = b1p[((4 * u + tt) * 2 + kf) * 64 + lane];
        V16 m;
#pragma unroll
        for (int j = 0; j < 4; ++j) {
          m.h[j]     = (__bf16)(bf2f(r.s[j])     * z0.f[j]);
          m.h[4 + j] = (__bf16)(bf2f(r.s[4 + j]) * z1.f[j]);
        }
        bz[tt][kf] = m.v;
      }
    }
#pragma unroll
    for (int rt = 0; rt < 2; ++rt) {
      const int rowA = rt * 16 + c;
      V16 af0, af1;
      af0.u = Wb[(d0 + rowA) * 8 + q];
      af1.u = Wb[(d0 + rowA) * 8 + 4 + q];
      f32x4 acc[4];
#pragma unroll
      for (int tt = 0; tt < 4; ++tt) acc[tt] = {0.f, 0.f, 0.f, 0.f};
#pragma unroll
      for (int tt = 0; tt < 4; ++tt) {
        acc[tt] = __builtin_amdgcn_mfma_f32_16x16x32_bf16(af0.v, bz[tt][0], acc[tt], 0, 0, 0);
        acc[tt] = __builtin_amdgcn_mfma_f32_16x16x32_bf16(af1.v, bz[tt][1], acc[tt], 0, 0, 0);
      }
      const int rwb = rt * 16 + 4 * q;
#pragma unroll
      for (int tt = 0; tt < 4; ++tt) {
        const int colb = (4 * u + tt) * 16 + c;
#pragma unroll
        for (int i = 0; i < 4; ++i) {
          V16 t; t.h[0] = (__bf16)fmaxf(acc[tt][i], 0.f);
          g1s[(rwb + i) * 328 + colb] = t.s[0];
        }
      }
    }
    __syncthreads();

    // ---- stage 3 ----
    f32x4 a3[4][2];
#pragma unroll
    for (int tt = 0; tt < 4; ++tt)
#pragma unroll
      for (int rt = 0; rt < 2; ++rt) a3[tt][rt] = {0.f, 0.f, 0.f, 0.f};
    for (int s = 0; s < 10; ++s) {
      V16 b[4];
#pragma unroll
      for (int tt = 0; tt < 4; ++tt) b[tt].u = b2p[((4 * u + tt) * 10 + s) * 64 + lane];
#pragma unroll
      for (int rt = 0; rt < 2; ++rt) {
        V16 a; a.u = *(const uint4*)&g1s[(rt * 16 + c) * 328 + s * 32 + q * 8];
#pragma unroll
        for (int tt = 0; tt < 4; ++tt)
          a3[tt][rt] = __builtin_amdgcn_mfma_f32_16x16x32_bf16(a.v, b[tt].v, a3[tt][rt], 0, 0, 0);
      }
    }
    float xacc[2][4];
#pragma unroll
    for (int rt = 0; rt < 2; ++rt)
#pragma unroll
      for (int i = 0; i < 4; ++i) xacc[rt][i] = 0.f;
#pragma unroll
    for (int tt = 0; tt < 4; ++tt) {
      const int col = (4 * u + tt) * 16 + c;
      const bool inb = (col < 300);
      const float bias = inb ? g2b[col] : 0.f;
#pragma unroll
      for (int rt = 0; rt < 2; ++rt)
#pragma unroll
        for (int i = 0; i < 4; ++i) {
          const float g2v = fmaxf(a3[tt][rt][i] + bias, 0.f);
          const float h = inb ? hw[(d0 + rt * 16 + 4 * q + i) * 300 + col] : 0.f;
          xacc[rt][i] += g2v * h;
        }
    }
#pragma unroll
    for (int rt = 0; rt < 2; ++rt)
#pragma unroll
      for (int i = 0; i < 4; ++i) {
        float t = xacc[rt][i];
        t += __shfl_xor(t, 1);
        t += __shfl_xor(t, 2);
        t += __shfl_xor(t, 4);
        t += __shfl_xor(t, 8);
        xacc[rt][i] = t;
      }
    __syncthreads();   // g1s reads done; alias as xred
    if (c < 4) {
#pragma unroll
      for (int rt = 0; rt < 2; ++rt) {
        float t = xacc[rt][0];
        t = (c == 1) ? xacc[rt][1] : t;
        t = (c == 2) ? xacc[rt][2] : t;
        t = (c == 3) ? xacc[rt][3] : t;
        xredf[u * 32 + rt * 16 + 4 * q + c] = t;
      }
    }
    __syncthreads();
    if (tid < 32) {
      float t = hb[d0 + tid];
#pragma unroll
      for (int uu = 0; uu < 5; ++uu) t += xredf[uu * 32 + tid];
      out[r0 + tid] = t;
    }
    __syncthreads();   // xredf reads done before next tile overwrites g1s
  }
}

extern "C" void kernel_launch(void* const* d_in, const int* in_sizes, int n_in,
                              void* d_out, int out_size, void* d_ws, size_t ws_size,
                              hipStream_t stream) {
  const float* x   = (const float*)d_in[0];
  const float* eps = (const float*)d_in[1];
  const float* W   = (const float*)d_in[2];
  const float* e1w = (const float*)d_in[3];
  const float* e1b = (const float*)d_in[4];
  const float* e2w = (const float*)d_in[5];
  const float* e2b = (const float*)d_in[6];
  const float* zmw = (const float*)d_in[7];
  const float* zmb = (const float*)d_in[8];
  const float* zvw = (const float*)d_in[9];
  const float* zvb = (const float*)d_in[10];
  const float* g1w = (const float*)d_in[11];
  const float* g2w = (const float*)d_in[12];
  const float* g2b = (const float*)d_in[13];
  const float* hw  = (const float*)d_in[14];
  const float* hb  = (const float*)d_in[15];
  float* out = (float*)d_out;
  uint4* ws4 = (uint4*)d_ws;

  // zero the grid-barrier counter (ws is poisoned 0xAA before every launch)
  hipMemsetAsync((char*)d_ws + (size_t)BAR_U4 * 16, 0, 4, stream);
  fused_kernel<<<NWG, NTHR, 0, stream>>>(x, eps, e1w, e1b, e2w, e2b,
                                         zmw, zmb, zvw, zvb, g1w, g2w,
                                         g2b, hw, hb, W, ws4, out);
}

// Round 10
// 351.917 us; speedup vs baseline: 1.3406x; 1.3406x over previous
//
#include <hip/hip_runtime.h>

typedef unsigned short u16;
typedef unsigned int u32;

typedef __bf16 bf16x8 __attribute__((ext_vector_type(8)));
typedef float f32x4 __attribute__((ext_vector_type(4)));

union V16 { uint4 u; bf16x8 v; u16 s[8]; __bf16 h[8]; };
union F4  { float4 v; float f[4]; };

__device__ __forceinline__ float bf2f(u16 a) {
  union { u32 u; float f; } c; c.u = ((u32)a) << 16; return c.f;
}

#define Z_OFF   131072
#define ZM_OFF  147456
#define ZLV_OFF 163840

// ws layout in uint4 units.
#define B1_OFF 0        // gen1_w frags: t<20, s<2
#define B2_OFF 2560     // gen2_w frags: t<20, s<10
#define E1_OFF 15360    // enc1_w frags: t<20, s<16
#define E2_OFF 35840    // enc2_w frags: t<20, s<10
#define ZMP_OFF 48640   // zm_w frags: t<4, s<10
#define ZVP_OFF 51200   // zv_w frags: t<4, s<10
#define FRAG_TOTAL 53760
#define WB4  53760      // W bf16 [512][64]   : 4096
#define XB4  57856      // x bf16 [256][512]  : 16384
#define H1_4 74240      // h1 bf16 [256][320] : 10240
#define H2_4 84480      // h2 bf16 [256][320] : 10240
#define PACK_ITEMS 74240
#define BAR_U4 94720    // barrier u32 lives at byte 94720*16
#define NWG 512
#define NTHR 320

__device__ __forceinline__ void pack_one(const float* __restrict__ src,
                                         int t, int s, int lane,
                                         int Nsrc, int Ksrc, int rowlen,
                                         uint4* __restrict__ dst) {
  const int n = t * 16 + (lane & 15);
  const int k0 = s * 32 + ((lane >> 4) << 3);
  V16 v;
#pragma unroll
  for (int j = 0; j < 8; ++j) {
    const int k = k0 + j;
    v.h[j] = (n < Nsrc && k < Ksrc) ? (__bf16)src[n * rowlen + k] : (__bf16)0.f;
  }
  *dst = v.u;
}

__device__ __forceinline__ void cvt8(const float* __restrict__ src, uint4* __restrict__ dst) {
  F4 a, b; a.v = *(const float4*)src; b.v = *(const float4*)(src + 4);
  V16 v;
#pragma unroll
  for (int j = 0; j < 4; ++j) { v.h[j] = (__bf16)a.f[j]; v.h[4 + j] = (__bf16)b.f[j]; }
  *dst = v.u;
}

// Software grid barrier. Release on the add publishes prior writes (L2
// writeback once per WG). Poll with RELAXED agent-scope loads: agent scope
// reads the LLC directly (sc1) but emits NO per-iteration cache invalidate —
// the R9 version polled with ACQUIRE and each poll invalidated L1/L2,
// thrashing every resident wave's working set (FETCH 4.5->57.7 MB). One
// acquire fence after the exit condition makes published data visible.
__device__ __forceinline__ void gbar(u32* bar, u32 target, int tid) {
  __syncthreads();
  if (tid == 0) {
    __hip_atomic_fetch_add(bar, 1u, __ATOMIC_RELEASE, __HIP_MEMORY_SCOPE_AGENT);
    u32 v;
    do {
      __builtin_amdgcn_s_sleep(8);
      v = __hip_atomic_load(bar, __ATOMIC_RELAXED, __HIP_MEMORY_SCOPE_AGENT);
    } while (v < target);
    __builtin_amdgcn_fence(__ATOMIC_ACQUIRE, "agent");
  }
  __syncthreads();
}

__global__ __launch_bounds__(NTHR, 4) void fused_kernel(
    const float* __restrict__ x, const float* __restrict__ eps,
    const float* __restrict__ e1w, const float* __restrict__ e1b,
    const float* __restrict__ e2w, const float* __restrict__ e2b,
    const float* __restrict__ zmw, const float* __restrict__ zmb,
    const float* __restrict__ zvw, const float* __restrict__ zvb,
    const float* __restrict__ g1w, const float* __restrict__ g2w,
    const float* __restrict__ g2b, const float* __restrict__ hw,
    const float* __restrict__ hb, const float* __restrict__ W,
    uint4* __restrict__ ws4, float* __restrict__ out) {
  __shared__ u16 g1s[32 * 328];     // 20,992 B
  __shared__ float xredf[5 * 32];   // separate: no alias with g1s

  u32* bar = (u32*)(ws4 + BAR_U4);
  const int wgid = blockIdx.x;
  const int tid = threadIdx.x;
  const int lane = tid & 63;
  const int q = lane >> 4;
  const int c = lane & 15;
  const int gw = wgid * 5 + (tid >> 6);   // global wave id (0..2559)

  // ---------------- P0: pack all fragment tables + Wb + xb ----------------
  {
    const int idx = wgid * NTHR + tid;
    if (idx < PACK_ITEMS) {
      const int l = idx & 63;
      if (idx < B2_OFF) {
        const int f = idx >> 6;
        pack_one(g1w, f >> 1, f & 1, l, 300, 64, 64, ws4 + idx);
      } else if (idx < E1_OFF) {
        const int f = (idx - B2_OFF) >> 6;
        pack_one(g2w, f / 10, f % 10, l, 300, 300, 300, ws4 + idx);
      } else if (idx < E2_OFF) {
        const int f = (idx - E1_OFF) >> 6;
        pack_one(e1w, f >> 4, f & 15, l, 300, 512, 512, ws4 + idx);
      } else if (idx < ZMP_OFF) {
        const int f = (idx - E2_OFF) >> 6;
        pack_one(e2w, f / 10, f % 10, l, 300, 300, 300, ws4 + idx);
      } else if (idx < ZVP_OFF) {
        const int f = (idx - ZMP_OFF) >> 6;
        pack_one(zmw, f / 10, f % 10, l, 64, 300, 300, ws4 + idx);
      } else if (idx < FRAG_TOTAL) {
        const int f = (idx - ZVP_OFF) >> 6;
        pack_one(zvw, f / 10, f % 10, l, 64, 300, 300, ws4 + idx);
      } else if (idx < XB4) {
        const int i = idx - WB4;
        cvt8(W + i * 8, ws4 + WB4 + i);
      } else {
        const int i = idx - XB4;
        cvt8(x + i * 8, ws4 + XB4 + i);
      }
    }
  }
  gbar(bar, 1 * NWG, tid);

  // ---------------- P1: enc1 (320 wave-jobs: rt<16 x nt<20) ----------------
  if (gw < 320) {
    const uint4* xb = ws4 + XB4;
    const uint4* e1p = ws4 + E1_OFF;
    u16* h1 = (u16*)(ws4 + H1_4);
    const int rt = gw / 20, nt = gw % 20;
    f32x4 acc = {0.f, 0.f, 0.f, 0.f};
    const int arow = rt * 16 + c;
#pragma unroll
    for (int s = 0; s < 16; ++s) {
      V16 a, b;
      a.u = xb[arow * 64 + s * 4 + q];
      b.u = e1p[(nt * 16 + s) * 64 + lane];
      acc = __builtin_amdgcn_mfma_f32_16x16x32_bf16(a.v, b.v, acc, 0, 0, 0);
    }
    const int col = nt * 16 + c;
    const float bias = (col < 300) ? e1b[col] : 0.f;
#pragma unroll
    for (int i = 0; i < 4; ++i) {
      const int row = rt * 16 + 4 * q + i;
      V16 t; t.h[0] = (col < 300) ? (__bf16)fmaxf(acc[i] + bias, 0.f) : (__bf16)0.f;
      h1[row * 320 + col] = t.s[0];
    }
  }
  gbar(bar, 2 * NWG, tid);

  // ---------------- P2: enc2 (320 wave-jobs) ----------------
  if (gw < 320) {
    const uint4* h1 = ws4 + H1_4;
    const uint4* e2p = ws4 + E2_OFF;
    u16* h2 = (u16*)(ws4 + H2_4);
    const int rt = gw / 20, nt = gw % 20;
    f32x4 acc = {0.f, 0.f, 0.f, 0.f};
    const int arow = rt * 16 + c;
#pragma unroll
    for (int s = 0; s < 10; ++s) {
      V16 a, b;
      a.u = h1[arow * 40 + s * 4 + q];
      b.u = e2p[(nt * 10 + s) * 64 + lane];
      acc = __builtin_amdgcn_mfma_f32_16x16x32_bf16(a.v, b.v, acc, 0, 0, 0);
    }
    const int col = nt * 16 + c;
    const float bias = (col < 300) ? e2b[col] : 0.f;
#pragma unroll
    for (int i = 0; i < 4; ++i) {
      const int row = rt * 16 + 4 * q + i;
      V16 t; t.h[0] = (col < 300) ? (__bf16)fmaxf(acc[i] + bias, 0.f) : (__bf16)0.f;
      h2[row * 320 + col] = t.s[0];
    }
  }
  gbar(bar, 3 * NWG, tid);

  // ---------------- P3: heads + reparameterize (64 wave-jobs) ----------------
  if (gw < 64) {
    const uint4* h2 = ws4 + H2_4;
    const uint4* zmp = ws4 + ZMP_OFF;
    const uint4* zvp = ws4 + ZVP_OFF;
    const int rt = gw >> 2, t = gw & 3;
    f32x4 am = {0.f, 0.f, 0.f, 0.f}, av = {0.f, 0.f, 0.f, 0.f};
    const int arow = rt * 16 + c;
#pragma unroll
    for (int s = 0; s < 10; ++s) {
      V16 a, bm, bv;
      a.u = h2[arow * 40 + s * 4 + q];
      bm.u = zmp[(t * 10 + s) * 64 + lane];
      bv.u = zvp[(t * 10 + s) * 64 + lane];
      am = __builtin_amdgcn_mfma_f32_16x16x32_bf16(a.v, bm.v, am, 0, 0, 0);
      av = __builtin_amdgcn_mfma_f32_16x16x32_bf16(a.v, bv.v, av, 0, 0, 0);
    }
    const int col = t * 16 + c;
    const float bm = zmb[col], bv = zvb[col];
#pragma unroll
    for (int i = 0; i < 4; ++i) {
      const int gi = (rt * 16 + 4 * q + i) * 64 + col;
      const float zm = am[i] + bm;
      const float zlv = av[i] + bv;
      out[ZM_OFF + gi] = zm;
      out[ZLV_OFF + gi] = zlv;
      out[Z_OFF + gi] = zm + eps[gi] * expf(0.5f * zlv);
    }
  }
  gbar(bar, 4 * NWG, tid);

  // ---------------- P4: decoder, 4096 virtual tiles, 8 per WG ----------------
  const float* z = out + Z_OFF;
  const uint4* Wb = ws4 + WB4;
  const uint4* b1p = ws4 + B1_OFF;
  const uint4* b2p = ws4 + B2_OFF;
  const int u = tid >> 6;

  for (int vt = wgid; vt < 4096; vt += NWG) {
    const int r0 = vt << 5;
    const int bi = vt >> 4;
    const int d0 = r0 & 511;
    const float* zrow = z + bi * 64;

    // ---- stage 2 ----
    bf16x8 bz[4][2];
#pragma unroll
    for (int kf = 0; kf < 2; ++kf) {
      F4 z0, z1;
      z0.v = *(const float4*)(zrow + kf * 32 + q * 8);
      z1.v = *(const float4*)(zrow + kf * 32 + q * 8 + 4);
#pragma unroll
      for (int tt = 0; tt < 4; ++tt) {
        V16 r; r.u = b1p[((4 * u + tt) * 2 + kf) * 64 + lane];
        V16 m;
#pragma unroll
        for (int j = 0; j < 4; ++j) {
          m.h[j]     = (__bf16)(bf2f(r.s[j])     * z0.f[j]);
          m.h[4 + j] = (__bf16)(bf2f(r.s[4 + j]) * z1.f[j]);
        }
        bz[tt][kf] = m.v;
      }
    }
#pragma unroll
    for (int rt = 0; rt < 2; ++rt) {
      const int rowA = rt * 16 + c;
      V16 af0, af1;
      af0.u = Wb[(d0 + rowA) * 8 + q];
      af1.u = Wb[(d0 + rowA) * 8 + 4 + q];
      f32x4 acc[4];
#pragma unroll
      for (int tt = 0; tt < 4; ++tt) acc[tt] = {0.f, 0.f, 0.f, 0.f};
#pragma unroll
      for (int tt = 0; tt < 4; ++tt) {
        acc[tt] = __builtin_amdgcn_mfma_f32_16x16x32_bf16(af0.v, bz[tt][0], acc[tt], 0, 0, 0);
        acc[tt] = __builtin_amdgcn_mfma_f32_16x16x32_bf16(af1.v, bz[tt][1], acc[tt], 0, 0, 0);
      }
      const int rwb = rt * 16 + 4 * q;
#pragma unroll
      for (int tt = 0; tt < 4; ++tt) {
        const int colb = (4 * u + tt) * 16 + c;
#pragma unroll
        for (int i = 0; i < 4; ++i) {
          V16 t; t.h[0] = (__bf16)fmaxf(acc[tt][i], 0.f);
          g1s[(rwb + i) * 328 + colb] = t.s[0];
        }
      }
    }
    __syncthreads();

    // ---- stage 3 ----
    f32x4 a3[4][2];
#pragma unroll
    for (int tt = 0; tt < 4; ++tt)
#pragma unroll
      for (int rt = 0; rt < 2; ++rt) a3[tt][rt] = {0.f, 0.f, 0.f, 0.f};
    for (int s = 0; s < 10; ++s) {
      V16 b[4];
#pragma unroll
      for (int tt = 0; tt < 4; ++tt) b[tt].u = b2p[((4 * u + tt) * 10 + s) * 64 + lane];
#pragma unroll
      for (int rt = 0; rt < 2; ++rt) {
        V16 a; a.u = *(const uint4*)&g1s[(rt * 16 + c) * 328 + s * 32 + q * 8];
#pragma unroll
        for (int tt = 0; tt < 4; ++tt)
          a3[tt][rt] = __builtin_amdgcn_mfma_f32_16x16x32_bf16(a.v, b[tt].v, a3[tt][rt], 0, 0, 0);
      }
    }
    float xacc[2][4];
#pragma unroll
    for (int rt = 0; rt < 2; ++rt)
#pragma unroll
      for (int i = 0; i < 4; ++i) xacc[rt][i] = 0.f;
#pragma unroll
    for (int tt = 0; tt < 4; ++tt) {
      const int col = (4 * u + tt) * 16 + c;
      const bool inb = (col < 300);
      const float bias = inb ? g2b[col] : 0.f;
#pragma unroll
      for (int rt = 0; rt < 2; ++rt)
#pragma unroll
        for (int i = 0; i < 4; ++i) {
          const float g2v = fmaxf(a3[tt][rt][i] + bias, 0.f);
          const float h = inb ? hw[(d0 + rt * 16 + 4 * q + i) * 300 + col] : 0.f;
          xacc[rt][i] += g2v * h;
        }
    }
#pragma unroll
    for (int rt = 0; rt < 2; ++rt)
#pragma unroll
      for (int i = 0; i < 4; ++i) {
        float t = xacc[rt][i];
        t += __shfl_xor(t, 1);
        t += __shfl_xor(t, 2);
        t += __shfl_xor(t, 4);
        t += __shfl_xor(t, 8);
        xacc[rt][i] = t;
      }
    if (c < 4) {
#pragma unroll
      for (int rt = 0; rt < 2; ++rt) {
        float t = xacc[rt][0];
        t = (c == 1) ? xacc[rt][1] : t;
        t = (c == 2) ? xacc[rt][2] : t;
        t = (c == 3) ? xacc[rt][3] : t;
        xredf[u * 32 + rt * 16 + 4 * q + c] = t;
      }
    }
    __syncthreads();   // xred writes + all g1s reads complete
    if (tid < 32) {
      float t = hb[d0 + tid];
#pragma unroll
      for (int uu = 0; uu < 5; ++uu) t += xredf[uu * 32 + tid];
      out[r0 + tid] = t;
    }
    // next iteration's g1s writes are fenced from this iteration's reads by
    // the barrier above; xredf writes of next iter are fenced by its own
    // barrier (which requires tid<32 to arrive after reading xredf here).
  }
}

extern "C" void kernel_launch(void* const* d_in, const int* in_sizes, int n_in,
                              void* d_out, int out_size, void* d_ws, size_t ws_size,
                              hipStream_t stream) {
  const float* x   = (const float*)d_in[0];
  const float* eps = (const float*)d_in[1];
  const float* W   = (const float*)d_in[2];
  const float* e1w = (const float*)d_in[3];
  const float* e1b = (const float*)d_in[4];
  const float* e2w = (const float*)d_in[5];
  const float* e2b = (const float*)d_in[6];
  const float* zmw = (const float*)d_in[7];
  const float* zmb = (const float*)d_in[8];
  const float* zvw = (const float*)d_in[9];
  const float* zvb = (const float*)d_in[10];
  const float* g1w = (const float*)d_in[11];
  const float* g2w = (const float*)d_in[12];
  const float* g2b = (const float*)d_in[13];
  const float* hw  = (const float*)d_in[14];
  const float* hb  = (const float*)d_in[15];
  float* out = (float*)d_out;
  uint4* ws4 = (uint4*)d_ws;

  // zero the grid-barrier counter (ws is poisoned 0xAA before every launch)
  hipMemsetAsync((char*)d_ws + (size_t)BAR_U4 * 16, 0, 4, stream);
  fused_kernel<<<NWG, NTHR, 0, stream>>>(x, eps, e1w, e1b, e2w, e2b,
                                         zmw, zmb, zvw, zvb, g1w, g2w,
                                         g2b, hw, hb, W, ws4, out);
}

// Round 11
// 180.365 us; speedup vs baseline: 2.6156x; 1.9511x over previous
//
#include <hip/hip_runtime.h>

typedef unsigned short u16;
typedef unsigned int u32;

typedef __bf16 bf16x8 __attribute__((ext_vector_type(8)));
typedef float f32x4 __attribute__((ext_vector_type(4)));

union V16 { uint4 u; bf16x8 v; u16 s[8]; __bf16 h[8]; };
union F4  { float4 v; float f[4]; };

__device__ __forceinline__ float bf2f(u16 a) {
  union { u32 u; float f; } c; c.u = ((u32)a) << 16; return c.f;
}

#define Z_OFF   131072
#define ZM_OFF  147456
#define ZLV_OFF 163840

// ws layout in uint4 units.
// Fragment packs (b-frag elem j of lane: B[k=s*32+(lane>>4)*8+j][n=t*16+(lane&15)]):
#define B1_OFF 0        // gen1_w frags: t<20, s<2
#define B2_OFF 2560     // gen2_w frags: t<20, s<10
#define E1_OFF 15360    // enc1_w frags: t<20, s<16
#define E2_OFF 35840    // enc2_w frags: t<20, s<10
#define ZMP_OFF 48640   // zm_w frags: t<4, s<10
#define ZVP_OFF 51200   // zv_w frags: t<4, s<10
#define FRAG_TOTAL 53760
#define WB4  53760      // W bf16 [512][64]   : 4096
#define XB4  57856      // x bf16 [256][512]  : 16384
#define H1_4 74240      // h1 bf16 [256][320] : 10240
#define H2_4 84480      // h2 bf16 [256][320] : 10240
#define PACK_THREADS 74240

__device__ __forceinline__ void pack_one(const float* __restrict__ src,
                                         int t, int s, int lane,
                                         int Nsrc, int Ksrc, int rowlen,
                                         uint4* __restrict__ dst) {
  const int n = t * 16 + (lane & 15);
  const int k0 = s * 32 + ((lane >> 4) << 3);
  V16 v;
#pragma unroll
  for (int j = 0; j < 8; ++j) {
    const int k = k0 + j;
    v.h[j] = (n < Nsrc && k < Ksrc) ? (__bf16)src[n * rowlen + k] : (__bf16)0.f;
  }
  *dst = v.u;
}

__device__ __forceinline__ void cvt8(const float* __restrict__ src, uint4* __restrict__ dst) {
  F4 a, b; a.v = *(const float4*)src; b.v = *(const float4*)(src + 4);
  V16 v;
#pragma unroll
  for (int j = 0; j < 4; ++j) { v.h[j] = (__bf16)a.f[j]; v.h[4 + j] = (__bf16)b.f[j]; }
  *dst = v.u;
}

__global__ __launch_bounds__(256) void pack_kernel(
    const float* __restrict__ g1w, const float* __restrict__ g2w,
    const float* __restrict__ e1w, const float* __restrict__ e2w,
    const float* __restrict__ zmw, const float* __restrict__ zvw,
    const float* __restrict__ W,   const float* __restrict__ x,
    uint4* __restrict__ ws4) {
  const int idx = blockIdx.x * 256 + threadIdx.x;
  if (idx >= PACK_THREADS) return;
  const int lane = idx & 63;
  if (idx < B2_OFF) {
    const int f = idx >> 6;
    pack_one(g1w, f >> 1, f & 1, lane, 300, 64, 64, ws4 + idx);
  } else if (idx < E1_OFF) {
    const int f = (idx - B2_OFF) >> 6;
    pack_one(g2w, f / 10, f % 10, lane, 300, 300, 300, ws4 + idx);
  } else if (idx < E2_OFF) {
    const int f = (idx - E1_OFF) >> 6;
    pack_one(e1w, f >> 4, f & 15, lane, 300, 512, 512, ws4 + idx);
  } else if (idx < ZMP_OFF) {
    const int f = (idx - E2_OFF) >> 6;
    pack_one(e2w, f / 10, f % 10, lane, 300, 300, 300, ws4 + idx);
  } else if (idx < ZVP_OFF) {
    const int f = (idx - ZMP_OFF) >> 6;
    pack_one(zmw, f / 10, f % 10, lane, 64, 300, 300, ws4 + idx);
  } else if (idx < FRAG_TOTAL) {
    const int f = (idx - ZVP_OFF) >> 6;
    pack_one(zvw, f / 10, f % 10, lane, 64, 300, 300, ws4 + idx);
  } else if (idx < XB4) {
    const int i = idx - WB4;
    cvt8(W + i * 8, ws4 + WB4 + i);
  } else {
    const int i = idx - XB4;
    cvt8(x + i * 8, ws4 + XB4 + i);
  }
}

// ---------------------------------------------------------------------------
// enc1: 320 WGs (rt 16 x nt 20) x 64 thr, fully unrolled K.
// ---------------------------------------------------------------------------
__global__ __launch_bounds__(64) void enc1_kernel(
    const uint4* __restrict__ xb, const uint4* __restrict__ e1p,
    const float* __restrict__ e1b, u16* __restrict__ h1) {
  const int wg = blockIdx.x;
  const int rt = wg / 20, nt = wg % 20;
  const int lane = threadIdx.x, q = lane >> 4, c = lane & 15;
  f32x4 acc = {0.f, 0.f, 0.f, 0.f};
  const int arow = rt * 16 + c;
#pragma unroll
  for (int s = 0; s < 16; ++s) {
    V16 a, b;
    a.u = xb[arow * 64 + s * 4 + q];
    b.u = e1p[(nt * 16 + s) * 64 + lane];
    acc = __builtin_amdgcn_mfma_f32_16x16x32_bf16(a.v, b.v, acc, 0, 0, 0);
  }
  const int col = nt * 16 + c;
  const float bias = (col < 300) ? e1b[col] : 0.f;
#pragma unroll
  for (int i = 0; i < 4; ++i) {
    const int row = rt * 16 + 4 * q + i;
    V16 t; t.h[0] = (col < 300) ? (__bf16)fmaxf(acc[i] + bias, 0.f) : (__bf16)0.f;
    h1[row * 320 + col] = t.s[0];
  }
}

__global__ __launch_bounds__(64) void enc2_kernel(
    const uint4* __restrict__ h1, const uint4* __restrict__ e2p,
    const float* __restrict__ e2b, u16* __restrict__ h2) {
  const int wg = blockIdx.x;
  const int rt = wg / 20, nt = wg % 20;
  const int lane = threadIdx.x, q = lane >> 4, c = lane & 15;
  f32x4 acc = {0.f, 0.f, 0.f, 0.f};
  const int arow = rt * 16 + c;
#pragma unroll
  for (int s = 0; s < 10; ++s) {
    V16 a, b;
    a.u = h1[arow * 40 + s * 4 + q];
    b.u = e2p[(nt * 10 + s) * 64 + lane];
    acc = __builtin_amdgcn_mfma_f32_16x16x32_bf16(a.v, b.v, acc, 0, 0, 0);
  }
  const int col = nt * 16 + c;
  const float bias = (col < 300) ? e2b[col] : 0.f;
#pragma unroll
  for (int i = 0; i < 4; ++i) {
    const int row = rt * 16 + 4 * q + i;
    V16 t; t.h[0] = (col < 300) ? (__bf16)fmaxf(acc[i] + bias, 0.f) : (__bf16)0.f;
    h2[row * 320 + col] = t.s[0];
  }
}

__global__ __launch_bounds__(64) void ench_kernel(
    const uint4* __restrict__ h2, const float* __restrict__ eps,
    const uint4* __restrict__ zmp, const float* __restrict__ zmb,
    const uint4* __restrict__ zvp, const float* __restrict__ zvb,
    float* __restrict__ out) {
  const int wg = blockIdx.x;
  const int rt = wg >> 2, t = wg & 3;
  const int lane = threadIdx.x, q = lane >> 4, c = lane & 15;
  f32x4 am = {0.f, 0.f, 0.f, 0.f}, av = {0.f, 0.f, 0.f, 0.f};
  const int arow = rt * 16 + c;
#pragma unroll
  for (int s = 0; s < 10; ++s) {
    V16 a, bm, bv;
    a.u = h2[arow * 40 + s * 4 + q];
    bm.u = zmp[(t * 10 + s) * 64 + lane];
    bv.u = zvp[(t * 10 + s) * 64 + lane];
    am = __builtin_amdgcn_mfma_f32_16x16x32_bf16(a.v, bm.v, am, 0, 0, 0);
    av = __builtin_amdgcn_mfma_f32_16x16x32_bf16(a.v, bv.v, av, 0, 0, 0);
  }
  const int col = t * 16 + c;
  const float bm = zmb[col], bv = zvb[col];
#pragma unroll
  for (int i = 0; i < 4; ++i) {
    const int gi = (rt * 16 + 4 * q + i) * 64 + col;
    const float zm = am[i] + bm;
    const float zlv = av[i] + bv;
    out[ZM_OFF + gi] = zm;
    out[ZLV_OFF + gi] = zlv;
    out[Z_OFF + gi] = zm + eps[gi] * expf(0.5f * zlv);
  }
}

// ---------------------------------------------------------------------------
// Fused decoder. 4096 WGs x 640 thr (10 waves). 32 rows/WG (one b).
// Wave u owns n-tiles {2u, 2u+1}; each b1p/b2p frag read once per WG.
// LDS = 20,992 B (xred aliases g1s after a barrier) -> 2 WGs/CU = 20 waves/CU
// (~59% occupancy vs R7's 10 waves). z-scaling on the A side (W rows), not B:
// halves the scaling VALU. __launch_bounds__(640,5) caps VGPR ~102 so the
// 20-wave residency is reachable.
// ---------------------------------------------------------------------------
__global__ __launch_bounds__(640, 5) void dec_kernel(
    const float* __restrict__ z,     // [256][64] (fp32, in d_out)
    const uint4* __restrict__ Wb,    // bf16 [512][64]
    const uint4* __restrict__ b1p,
    const uint4* __restrict__ b2p,
    const float* __restrict__ g2b,
    const float* __restrict__ hw,    // [512][300] fp32
    const float* __restrict__ hb,
    float* __restrict__ xout) {
  __shared__ u16 g1s[32 * 328];     // 20,992 B; xred aliases after barrier
  float* xredf = (float*)g1s;       // [10][32] floats = 1,280 B

  const int wg = blockIdx.x;
  const int r0 = wg << 5;
  const int bi = wg >> 4;
  const int d0 = r0 & 511;
  const int tid = threadIdx.x;
  const int u = tid >> 6;           // wave 0..9: n-tiles 2u, 2u+1
  const int lane = tid & 63;
  const int q = lane >> 4;
  const int c = lane & 15;

  const float* zrow = z + bi * 64;

  // ---- stage 2: A = bf16(W row) * z, B = raw b1p frags ----
  // z values needed by this lane: k = kf*32 + q*8 + j
  F4 z0a, z0b, z1a, z1b;
  z0a.v = *(const float4*)(zrow + q * 8);
  z0b.v = *(const float4*)(zrow + q * 8 + 4);
  z1a.v = *(const float4*)(zrow + 32 + q * 8);
  z1b.v = *(const float4*)(zrow + 32 + q * 8 + 4);

  bf16x8 af[2][2];   // [rt][kf]
#pragma unroll
  for (int rt = 0; rt < 2; ++rt) {
    V16 w0, w1, m;
    w0.u = Wb[(d0 + rt * 16 + c) * 8 + q];        // k = q*8..q*8+7
    w1.u = Wb[(d0 + rt * 16 + c) * 8 + 4 + q];    // k = 32+q*8..
#pragma unroll
    for (int j = 0; j < 4; ++j) {
      m.h[j]     = (__bf16)(bf2f(w0.s[j])     * z0a.f[j]);
      m.h[4 + j] = (__bf16)(bf2f(w0.s[4 + j]) * z0b.f[j]);
    }
    af[rt][0] = m.v;
#pragma unroll
    for (int j = 0; j < 4; ++j) {
      m.h[j]     = (__bf16)(bf2f(w1.s[j])     * z1a.f[j]);
      m.h[4 + j] = (__bf16)(bf2f(w1.s[4 + j]) * z1b.f[j]);
    }
    af[rt][1] = m.v;
  }
  {
    f32x4 acc[2][2];   // [ttl][rt]
#pragma unroll
    for (int ttl = 0; ttl < 2; ++ttl)
#pragma unroll
      for (int rt = 0; rt < 2; ++rt) acc[ttl][rt] = {0.f, 0.f, 0.f, 0.f};
#pragma unroll
    for (int ttl = 0; ttl < 2; ++ttl) {
      V16 b0, b1;
      b0.u = b1p[((2 * u + ttl) * 2 + 0) * 64 + lane];
      b1.u = b1p[((2 * u + ttl) * 2 + 1) * 64 + lane];
#pragma unroll
      for (int rt = 0; rt < 2; ++rt) {
        acc[ttl][rt] = __builtin_amdgcn_mfma_f32_16x16x32_bf16(af[rt][0], b0.v, acc[ttl][rt], 0, 0, 0);
        acc[ttl][rt] = __builtin_amdgcn_mfma_f32_16x16x32_bf16(af[rt][1], b1.v, acc[ttl][rt], 0, 0, 0);
      }
    }
#pragma unroll
    for (int ttl = 0; ttl < 2; ++ttl) {
      const int colb = (2 * u + ttl) * 16 + c;
#pragma unroll
      for (int rt = 0; rt < 2; ++rt) {
        const int rwb = rt * 16 + 4 * q;
#pragma unroll
        for (int i = 0; i < 4; ++i) {
          V16 t; t.h[0] = (__bf16)fmaxf(acc[ttl][rt][i], 0.f);
          g1s[(rwb + i) * 328 + colb] = t.s[0];
        }
      }
    }
  }
  __syncthreads();

  // ---- stage 3: GEMM2 (tiles 2u, 2u+1) + fused head dot ----
  f32x4 a3[2][2];   // [ttl][rt]
#pragma unroll
  for (int ttl = 0; ttl < 2; ++ttl)
#pragma unroll
    for (int rt = 0; rt < 2; ++rt) a3[ttl][rt] = {0.f, 0.f, 0.f, 0.f};
  for (int s = 0; s < 10; ++s) {
    V16 b0, b1;
    b0.u = b2p[((2 * u + 0) * 10 + s) * 64 + lane];
    b1.u = b2p[((2 * u + 1) * 10 + s) * 64 + lane];
#pragma unroll
    for (int rt = 0; rt < 2; ++rt) {
      V16 a; a.u = *(const uint4*)&g1s[(rt * 16 + c) * 328 + s * 32 + q * 8];
      a3[0][rt] = __builtin_amdgcn_mfma_f32_16x16x32_bf16(a.v, b0.v, a3[0][rt], 0, 0, 0);
      a3[1][rt] = __builtin_amdgcn_mfma_f32_16x16x32_bf16(a.v, b1.v, a3[1][rt], 0, 0, 0);
    }
  }
  float xacc[2][4];   // [rt][i]
#pragma unroll
  for (int rt = 0; rt < 2; ++rt)
#pragma unroll
    for (int i = 0; i < 4; ++i) xacc[rt][i] = 0.f;
#pragma unroll
  for (int ttl = 0; ttl < 2; ++ttl) {
    const int col = (2 * u + ttl) * 16 + c;
    const bool inb = (col < 300);
    const float bias = inb ? g2b[col] : 0.f;
#pragma unroll
    for (int rt = 0; rt < 2; ++rt)
#pragma unroll
      for (int i = 0; i < 4; ++i) {
        const float g2v = fmaxf(a3[ttl][rt][i] + bias, 0.f);
        const float h = inb ? hw[(d0 + rt * 16 + 4 * q + i) * 300 + col] : 0.f;
        xacc[rt][i] += g2v * h;
      }
  }
#pragma unroll
  for (int rt = 0; rt < 2; ++rt)
#pragma unroll
    for (int i = 0; i < 4; ++i) {
      float t = xacc[rt][i];
      t += __shfl_xor(t, 1);
      t += __shfl_xor(t, 2);
      t += __shfl_xor(t, 4);
      t += __shfl_xor(t, 8);
      xacc[rt][i] = t;
    }
  __syncthreads();   // all g1s reads complete; alias as xred
  if (c < 4) {
#pragma unroll
    for (int rt = 0; rt < 2; ++rt) {
      float t = xacc[rt][0];
      t = (c == 1) ? xacc[rt][1] : t;
      t = (c == 2) ? xacc[rt][2] : t;
      t = (c == 3) ? xacc[rt][3] : t;
      xredf[u * 32 + rt * 16 + 4 * q + c] = t;
    }
  }
  __syncthreads();
  if (tid < 32) {
    float t = hb[d0 + tid];
#pragma unroll
    for (int uu = 0; uu < 10; ++uu) t += xredf[uu * 32 + tid];
    xout[r0 + tid] = t;
  }
}

extern "C" void kernel_launch(void* const* d_in, const int* in_sizes, int n_in,
                              void* d_out, int out_size, void* d_ws, size_t ws_size,
                              hipStream_t stream) {
  const float* x   = (const float*)d_in[0];
  const float* eps = (const float*)d_in[1];
  const float* W   = (const float*)d_in[2];
  const float* e1w = (const float*)d_in[3];
  const float* e1b = (const float*)d_in[4];
  const float* e2w = (const float*)d_in[5];
  const float* e2b = (const float*)d_in[6];
  const float* zmw = (const float*)d_in[7];
  const float* zmb = (const float*)d_in[8];
  const float* zvw = (const float*)d_in[9];
  const float* zvb = (const float*)d_in[10];
  const float* g1w = (const float*)d_in[11];
  const float* g2w = (const float*)d_in[12];
  const float* g2b = (const float*)d_in[13];
  const float* hw  = (const float*)d_in[14];
  const float* hb  = (const float*)d_in[15];
  float* out = (float*)d_out;
  uint4* ws4 = (uint4*)d_ws;

  pack_kernel<<<(PACK_THREADS + 255) / 256, 256, 0, stream>>>(
      g1w, g2w, e1w, e2w, zmw, zvw, W, x, ws4);
  enc1_kernel<<<320, 64, 0, stream>>>(ws4 + XB4, ws4 + E1_OFF, e1b, (u16*)(ws4 + H1_4));
  enc2_kernel<<<320, 64, 0, stream>>>(ws4 + H1_4, ws4 + E2_OFF, e2b, (u16*)(ws4 + H2_4));
  ench_kernel<<<64, 64, 0, stream>>>(ws4 + H2_4, eps,
                                     ws4 + ZMP_OFF, zmb, ws4 + ZVP_OFF, zvb, out);
  dec_kernel<<<4096, 640, 0, stream>>>(out + Z_OFF, ws4 + WB4,
                                       ws4 + B1_OFF, ws4 + B2_OFF,
                                       g2b, hw, hb, out);
}

// Round 12
// 175.765 us; speedup vs baseline: 2.6841x; 1.0262x over previous
//
#include <hip/hip_runtime.h>

typedef unsigned short u16;
typedef unsigned int u32;

typedef __bf16 bf16x8 __attribute__((ext_vector_type(8)));
typedef float f32x4 __attribute__((ext_vector_type(4)));

union V16 { uint4 u; bf16x8 v; u16 s[8]; __bf16 h[8]; };
union F4  { float4 v; float f[4]; };

__device__ __forceinline__ float bf2f(u16 a) {
  union { u32 u; float f; } c; c.u = ((u32)a) << 16; return c.f;
}

#define Z_OFF   131072
#define ZM_OFF  147456
#define ZLV_OFF 163840

// ws layout in uint4 units.
// Fragment packs (b-frag elem j of lane: B[k=s*32+(lane>>4)*8+j][n=t*16+(lane&15)]):
#define B1_OFF 0        // gen1_w frags: t<20, s<2
#define B2_OFF 2560     // gen2_w frags: t<20, s<10
#define E1_OFF 15360    // enc1_w frags: t<20, s<16
#define E2_OFF 35840    // enc2_w frags: t<20, s<10
#define ZMP_OFF 48640   // zm_w frags: t<4, s<10
#define ZVP_OFF 51200   // zv_w frags: t<4, s<10
#define FRAG_TOTAL 53760
#define WB4  53760      // W bf16 [512][64]   : 4096
#define XB4  57856      // x bf16 [256][512]  : 16384
#define H1_4 74240      // h1 bf16 [256][320] : 10240
#define H2_4 84480      // h2 bf16 [256][320] : 10240
#define PACK_THREADS 74240

__device__ __forceinline__ void pack_one(const float* __restrict__ src,
                                         int t, int s, int lane,
                                         int Nsrc, int Ksrc, int rowlen,
                                         uint4* __restrict__ dst) {
  const int n = t * 16 + (lane & 15);
  const int k0 = s * 32 + ((lane >> 4) << 3);
  V16 v;
#pragma unroll
  for (int j = 0; j < 8; ++j) {
    const int k = k0 + j;
    v.h[j] = (n < Nsrc && k < Ksrc) ? (__bf16)src[n * rowlen + k] : (__bf16)0.f;
  }
  *dst = v.u;
}

__device__ __forceinline__ void cvt8(const float* __restrict__ src, uint4* __restrict__ dst) {
  F4 a, b; a.v = *(const float4*)src; b.v = *(const float4*)(src + 4);
  V16 v;
#pragma unroll
  for (int j = 0; j < 4; ++j) { v.h[j] = (__bf16)a.f[j]; v.h[4 + j] = (__bf16)b.f[j]; }
  *dst = v.u;
}

__global__ __launch_bounds__(256) void pack_kernel(
    const float* __restrict__ g1w, const float* __restrict__ g2w,
    const float* __restrict__ e1w, const float* __restrict__ e2w,
    const float* __restrict__ zmw, const float* __restrict__ zvw,
    const float* __restrict__ W,   const float* __restrict__ x,
    uint4* __restrict__ ws4) {
  const int idx = blockIdx.x * 256 + threadIdx.x;
  if (idx >= PACK_THREADS) return;
  const int lane = idx & 63;
  if (idx < B2_OFF) {
    const int f = idx >> 6;
    pack_one(g1w, f >> 1, f & 1, lane, 300, 64, 64, ws4 + idx);
  } else if (idx < E1_OFF) {
    const int f = (idx - B2_OFF) >> 6;
    pack_one(g2w, f / 10, f % 10, lane, 300, 300, 300, ws4 + idx);
  } else if (idx < E2_OFF) {
    const int f = (idx - E1_OFF) >> 6;
    pack_one(e1w, f >> 4, f & 15, lane, 300, 512, 512, ws4 + idx);
  } else if (idx < ZMP_OFF) {
    const int f = (idx - E2_OFF) >> 6;
    pack_one(e2w, f / 10, f % 10, lane, 300, 300, 300, ws4 + idx);
  } else if (idx < ZVP_OFF) {
    const int f = (idx - ZMP_OFF) >> 6;
    pack_one(zmw, f / 10, f % 10, lane, 64, 300, 300, ws4 + idx);
  } else if (idx < FRAG_TOTAL) {
    const int f = (idx - ZVP_OFF) >> 6;
    pack_one(zvw, f / 10, f % 10, lane, 64, 300, 300, ws4 + idx);
  } else if (idx < XB4) {
    const int i = idx - WB4;
    cvt8(W + i * 8, ws4 + WB4 + i);
  } else {
    const int i = idx - XB4;
    cvt8(x + i * 8, ws4 + XB4 + i);
  }
}

// ---------------------------------------------------------------------------
// enc1: 320 WGs (rt 16 x nt 20) x 64 thr, fully unrolled K.
// ---------------------------------------------------------------------------
__global__ __launch_bounds__(64) void enc1_kernel(
    const uint4* __restrict__ xb, const uint4* __restrict__ e1p,
    const float* __restrict__ e1b, u16* __restrict__ h1) {
  const int wg = blockIdx.x;
  const int rt = wg / 20, nt = wg % 20;
  const int lane = threadIdx.x, q = lane >> 4, c = lane & 15;
  f32x4 acc = {0.f, 0.f, 0.f, 0.f};
  const int arow = rt * 16 + c;
#pragma unroll
  for (int s = 0; s < 16; ++s) {
    V16 a, b;
    a.u = xb[arow * 64 + s * 4 + q];
    b.u = e1p[(nt * 16 + s) * 64 + lane];
    acc = __builtin_amdgcn_mfma_f32_16x16x32_bf16(a.v, b.v, acc, 0, 0, 0);
  }
  const int col = nt * 16 + c;
  const float bias = (col < 300) ? e1b[col] : 0.f;
#pragma unroll
  for (int i = 0; i < 4; ++i) {
    const int row = rt * 16 + 4 * q + i;
    V16 t; t.h[0] = (col < 300) ? (__bf16)fmaxf(acc[i] + bias, 0.f) : (__bf16)0.f;
    h1[row * 320 + col] = t.s[0];
  }
}

__global__ __launch_bounds__(64) void enc2_kernel(
    const uint4* __restrict__ h1, const uint4* __restrict__ e2p,
    const float* __restrict__ e2b, u16* __restrict__ h2) {
  const int wg = blockIdx.x;
  const int rt = wg / 20, nt = wg % 20;
  const int lane = threadIdx.x, q = lane >> 4, c = lane & 15;
  f32x4 acc = {0.f, 0.f, 0.f, 0.f};
  const int arow = rt * 16 + c;
#pragma unroll
  for (int s = 0; s < 10; ++s) {
    V16 a, b;
    a.u = h1[arow * 40 + s * 4 + q];
    b.u = e2p[(nt * 10 + s) * 64 + lane];
    acc = __builtin_amdgcn_mfma_f32_16x16x32_bf16(a.v, b.v, acc, 0, 0, 0);
  }
  const int col = nt * 16 + c;
  const float bias = (col < 300) ? e2b[col] : 0.f;
#pragma unroll
  for (int i = 0; i < 4; ++i) {
    const int row = rt * 16 + 4 * q + i;
    V16 t; t.h[0] = (col < 300) ? (__bf16)fmaxf(acc[i] + bias, 0.f) : (__bf16)0.f;
    h2[row * 320 + col] = t.s[0];
  }
}

__global__ __launch_bounds__(64) void ench_kernel(
    const uint4* __restrict__ h2, const float* __restrict__ eps,
    const uint4* __restrict__ zmp, const float* __restrict__ zmb,
    const uint4* __restrict__ zvp, const float* __restrict__ zvb,
    float* __restrict__ out) {
  const int wg = blockIdx.x;
  const int rt = wg >> 2, t = wg & 3;
  const int lane = threadIdx.x, q = lane >> 4, c = lane & 15;
  f32x4 am = {0.f, 0.f, 0.f, 0.f}, av = {0.f, 0.f, 0.f, 0.f};
  const int arow = rt * 16 + c;
#pragma unroll
  for (int s = 0; s < 10; ++s) {
    V16 a, bm, bv;
    a.u = h2[arow * 40 + s * 4 + q];
    bm.u = zmp[(t * 10 + s) * 64 + lane];
    bv.u = zvp[(t * 10 + s) * 64 + lane];
    am = __builtin_amdgcn_mfma_f32_16x16x32_bf16(a.v, bm.v, am, 0, 0, 0);
    av = __builtin_amdgcn_mfma_f32_16x16x32_bf16(a.v, bv.v, av, 0, 0, 0);
  }
  const int col = t * 16 + c;
  const float bm = zmb[col], bv = zvb[col];
#pragma unroll
  for (int i = 0; i < 4; ++i) {
    const int gi = (rt * 16 + 4 * q + i) * 64 + col;
    const float zm = am[i] + bm;
    const float zlv = av[i] + bv;
    out[ZM_OFF + gi] = zm;
    out[ZLV_OFF + gi] = zlv;
    out[Z_OFF + gi] = zm + eps[gi] * expf(0.5f * zlv);
  }
}

// ---------------------------------------------------------------------------
// Fused decoder — R7 structure (320 thr, 5 waves, 32 rows/WG, 21 KB LDS,
// 2 WGs/CU) + 2-deep register double-buffer on the b2p fragment stream.
// bp[0] (s=0) is issued BEFORE stage 2's MFMA block so the first L2 round
// trip hides under stage 2 + the barrier; thereafter s+1 loads issue before
// the 8 MFMAs of step s. No hw/g2b hoist (R8 evidence: hoist regressed).
// ---------------------------------------------------------------------------
__global__ __launch_bounds__(320, 3) void dec_kernel(
    const float* __restrict__ z,     // [256][64] (fp32, in d_out)
    const uint4* __restrict__ Wb,    // bf16 [512][64]
    const uint4* __restrict__ b1p,
    const uint4* __restrict__ b2p,
    const float* __restrict__ g2b,
    const float* __restrict__ hw,    // [512][300] fp32
    const float* __restrict__ hb,
    float* __restrict__ xout) {
  __shared__ u16 g1s[32 * 328];     // 20,992 B (reused as xred after barrier)
  float* xredf = (float*)g1s;

  const int wg = blockIdx.x;
  const int r0 = wg << 5;
  const int bi = wg >> 4;
  const int d0 = r0 & 511;
  const int tid = threadIdx.x;
  const int u = tid >> 6;           // wave: n-tiles 4u..4u+3
  const int lane = tid & 63;
  const int q = lane >> 4;
  const int c = lane & 15;

  const float* zrow = z + bi * 64;

  // ---- early-issue the first b2p fragment set (consumed in stage 3) ----
  V16 bp[2][4];
#pragma unroll
  for (int tt = 0; tt < 4; ++tt)
    bp[0][tt].u = b2p[((4 * u + tt) * 10 + 0) * 64 + lane];

  // ---- stage 2 ----
  bf16x8 bz[4][2];
#pragma unroll
  for (int kf = 0; kf < 2; ++kf) {
    F4 z0, z1;
    z0.v = *(const float4*)(zrow + kf * 32 + q * 8);
    z1.v = *(const float4*)(zrow + kf * 32 + q * 8 + 4);
#pragma unroll
    for (int tt = 0; tt < 4; ++tt) {
      V16 r; r.u = b1p[((4 * u + tt) * 2 + kf) * 64 + lane];
      V16 m;
#pragma unroll
      for (int j = 0; j < 4; ++j) {
        m.h[j]     = (__bf16)(bf2f(r.s[j])     * z0.f[j]);
        m.h[4 + j] = (__bf16)(bf2f(r.s[4 + j]) * z1.f[j]);
      }
      bz[tt][kf] = m.v;
    }
  }
#pragma unroll
  for (int rt = 0; rt < 2; ++rt) {
    const int rowA = rt * 16 + c;
    V16 af0, af1;
    af0.u = Wb[(d0 + rowA) * 8 + q];
    af1.u = Wb[(d0 + rowA) * 8 + 4 + q];
    f32x4 acc[4];
#pragma unroll
    for (int tt = 0; tt < 4; ++tt) acc[tt] = {0.f, 0.f, 0.f, 0.f};
#pragma unroll
    for (int tt = 0; tt < 4; ++tt) {
      acc[tt] = __builtin_amdgcn_mfma_f32_16x16x32_bf16(af0.v, bz[tt][0], acc[tt], 0, 0, 0);
      acc[tt] = __builtin_amdgcn_mfma_f32_16x16x32_bf16(af1.v, bz[tt][1], acc[tt], 0, 0, 0);
    }
    const int rwb = rt * 16 + 4 * q;
#pragma unroll
    for (int tt = 0; tt < 4; ++tt) {
      const int colb = (4 * u + tt) * 16 + c;
#pragma unroll
      for (int i = 0; i < 4; ++i) {
        V16 t; t.h[0] = (__bf16)fmaxf(acc[tt][i], 0.f);
        g1s[(rwb + i) * 328 + colb] = t.s[0];
      }
    }
  }
  __syncthreads();

  // ---- stage 3: 2-deep pipelined b2p stream ----
  f32x4 a3[4][2];
#pragma unroll
  for (int tt = 0; tt < 4; ++tt)
#pragma unroll
    for (int rt = 0; rt < 2; ++rt) a3[tt][rt] = {0.f, 0.f, 0.f, 0.f};
  for (int s = 0; s < 10; ++s) {
    const int cur = s & 1, nxt = cur ^ 1;
    if (s < 9) {
#pragma unroll
      for (int tt = 0; tt < 4; ++tt)
        bp[nxt][tt].u = b2p[((4 * u + tt) * 10 + s + 1) * 64 + lane];
    }
#pragma unroll
    for (int rt = 0; rt < 2; ++rt) {
      V16 a; a.u = *(const uint4*)&g1s[(rt * 16 + c) * 328 + s * 32 + q * 8];
#pragma unroll
      for (int tt = 0; tt < 4; ++tt)
        a3[tt][rt] = __builtin_amdgcn_mfma_f32_16x16x32_bf16(a.v, bp[cur][tt].v, a3[tt][rt], 0, 0, 0);
    }
  }
  float xacc[2][4];
#pragma unroll
  for (int rt = 0; rt < 2; ++rt)
#pragma unroll
    for (int i = 0; i < 4; ++i) xacc[rt][i] = 0.f;
#pragma unroll
  for (int tt = 0; tt < 4; ++tt) {
    const int col = (4 * u + tt) * 16 + c;
    const bool inb = (col < 300);
    const float bias = inb ? g2b[col] : 0.f;
#pragma unroll
    for (int rt = 0; rt < 2; ++rt)
#pragma unroll
      for (int i = 0; i < 4; ++i) {
        const float g2v = fmaxf(a3[tt][rt][i] + bias, 0.f);
        const float h = inb ? hw[(d0 + rt * 16 + 4 * q + i) * 300 + col] : 0.f;
        xacc[rt][i] += g2v * h;
      }
  }
#pragma unroll
  for (int rt = 0; rt < 2; ++rt)
#pragma unroll
    for (int i = 0; i < 4; ++i) {
      float t = xacc[rt][i];
      t += __shfl_xor(t, 1);
      t += __shfl_xor(t, 2);
      t += __shfl_xor(t, 4);
      t += __shfl_xor(t, 8);
      xacc[rt][i] = t;
    }
  __syncthreads();   // all waves done reading g1s; safe to alias as xred
  if (c < 4) {
#pragma unroll
    for (int rt = 0; rt < 2; ++rt) {
      float t = xacc[rt][0];
      t = (c == 1) ? xacc[rt][1] : t;
      t = (c == 2) ? xacc[rt][2] : t;
      t = (c == 3) ? xacc[rt][3] : t;
      xredf[u * 32 + rt * 16 + 4 * q + c] = t;
    }
  }
  __syncthreads();
  if (tid < 32) {
    float t = hb[d0 + tid];
#pragma unroll
    for (int uu = 0; uu < 5; ++uu) t += xredf[uu * 32 + tid];
    xout[r0 + tid] = t;
  }
}

extern "C" void kernel_launch(void* const* d_in, const int* in_sizes, int n_in,
                              void* d_out, int out_size, void* d_ws, size_t ws_size,
                              hipStream_t stream) {
  const float* x   = (const float*)d_in[0];
  const float* eps = (const float*)d_in[1];
  const float* W   = (const float*)d_in[2];
  const float* e1w = (const float*)d_in[3];
  const float* e1b = (const float*)d_in[4];
  const float* e2w = (const float*)d_in[5];
  const float* e2b = (const float*)d_in[6];
  const float* zmw = (const float*)d_in[7];
  const float* zmb = (const float*)d_in[8];
  const float* zvw = (const float*)d_in[9];
  const float* zvb = (const float*)d_in[10];
  const float* g1w = (const float*)d_in[11];
  const float* g2w = (const float*)d_in[12];
  const float* g2b = (const float*)d_in[13];
  const float* hw  = (const float*)d_in[14];
  const float* hb  = (const float*)d_in[15];
  float* out = (float*)d_out;
  uint4* ws4 = (uint4*)d_ws;

  pack_kernel<<<(PACK_THREADS + 255) / 256, 256, 0, stream>>>(
      g1w, g2w, e1w, e2w, zmw, zvw, W, x, ws4);
  enc1_kernel<<<320, 64, 0, stream>>>(ws4 + XB4, ws4 + E1_OFF, e1b, (u16*)(ws4 + H1_4));
  enc2_kernel<<<320, 64, 0, stream>>>(ws4 + H1_4, ws4 + E2_OFF, e2b, (u16*)(ws4 + H2_4));
  ench_kernel<<<64, 64, 0, stream>>>(ws4 + H2_4, eps,
                                     ws4 + ZMP_OFF, zmb, ws4 + ZVP_OFF, zvb, out);
  dec_kernel<<<4096, 320, 0, stream>>>(out + Z_OFF, ws4 + WB4,
                                       ws4 + B1_OFF, ws4 + B2_OFF,
                                       g2b, hw, hb, out);
}